// Round 10
// baseline (575.743 us; speedup 1.0000x reference)
//
#include <hip/hip_runtime.h>

// StatefulFormantFilter: B=32, T=48000, F=5
// y[t] = x[t] + 2 r cos(th) y[t-1] - r^2 y[t-2],  r=exp(-pi bw/SR), th=2 pi cf/SR
// x = excitation * (1-r^2) sin(th);  out = sum_f y;  new_states = (y[T-1], y[T-2])
//
// R10: SINGLE-PASS chained scan with decoupled look-back (no grid.sync —
// R8 showed cg grid.sync costs ~75us; device-scope atomics are cheap):
//  - ticket counter assigns virtual block ids => look-back is deadlock-free
//    (a block only spins on strictly lower tickets).
//  - per block (b, 64-chunk group): build chunk maps (pipelined loads),
//    in-LDS wave-per-formant inclusive scan (maps stay LDS-resident),
//    lane63 publishes 6-float group aggregate + release flag,
//    look-back composes predecessor aggregates with ONE wave-scan (lane i =
//    group i, identity pads), entering states -> replay 16 steps per chunk
//    (inputs L1/L2-hot), f-sum via padded LDS, coalesced stores.
//  - g==NG-1 block writes new_states. No Aws, no second input sweep.

constexpr int B = 32;
constexpr int T = 48000;
constexpr int F = 5;
constexpr int L = 16;          // chunk length
constexpr int C = T / L;       // 3000 chunks per chain
constexpr int GS = 64;         // chunks per group (one wave per formant)
constexpr int NG = (C + GS - 1) / GS;  // 47 groups per chain (<= 64!)
constexpr int NCHAIN = B * F;  // 160
constexpr int THREADS = GS * F;        // 320 = 5 waves
constexpr int NBG = B * NG;            // 1504 blocks
constexpr int MSTRIDE = 7;             // map stride in floats
constexpr int MROW = GS * MSTRIDE + 1; // 449: row ≡ 1 mod 32 -> bank spread
constexpr int RROW = GS * (L + 1) + 1; // 1089

#define CBW2 (-9.4416635e-05f)   // -pi/(48000*ln2)
#define CCF  (1.3089969e-04f)    // 2*pi/48000

__device__ __forceinline__ float fast_exp2(float x) {
#if __has_builtin(__builtin_amdgcn_exp2f)
  return __builtin_amdgcn_exp2f(x);
#else
  return exp2f(x);
#endif
}

__device__ __forceinline__ void coef(float cff, float bwf, float e,
                                     float& p, float& q, float& x) {
  float r  = fast_exp2(CBW2 * bwf);
  float th = CCF * cff;
  float sn = __sinf(th);
  float cs = __cosf(th);
  p = 2.f * r * cs;            // -a1
  q = -r * r;                  // -a2
  x = e * fmaf(q, sn, sn);     // e * (1-r^2) sin(th)
}

// Inclusive Hillis-Steele scan of affine maps across a wave.
// lane order = time order; result at lane i = M_i ∘ ... ∘ M_0.
__device__ __forceinline__ void wave_scan_maps(int lane, float& u1, float& u2,
                                               float& v1, float& v2,
                                               float& w1, float& w2) {
  #pragma unroll
  for (int d = 1; d < 64; d <<= 1) {
    float pu1 = __shfl_up(u1, d);
    float pv1 = __shfl_up(v1, d);
    float pu2 = __shfl_up(u2, d);
    float pv2 = __shfl_up(v2, d);
    float pw1 = __shfl_up(w1, d);
    float pw2 = __shfl_up(w2, d);
    bool has = (lane >= d);
    pu1 = has ? pu1 : 1.f;  pv1 = has ? pv1 : 0.f;
    pu2 = has ? pu2 : 0.f;  pv2 = has ? pv2 : 1.f;
    pw1 = has ? pw1 : 0.f;  pw2 = has ? pw2 : 0.f;
    float nu1 = fmaf(u1, pu1, v1 * pu2);
    float nv1 = fmaf(u1, pv1, v1 * pv2);
    float nu2 = fmaf(u2, pu1, v2 * pu2);
    float nv2 = fmaf(u2, pv1, v2 * pv2);
    float nw1 = fmaf(u1, pw1, fmaf(v1, pw2, w1));
    float nw2 = fmaf(u2, pw1, fmaf(v2, pw2, w2));
    u1 = nu1; v1 = nv1; u2 = nu2; v2 = nv2; w1 = nw1; w2 = nw2;
  }
}

__global__ __launch_bounds__(THREADS) void fused_kernel(
    const float* __restrict__ exc, const float* __restrict__ cf,
    const float* __restrict__ bw, const float* __restrict__ states0,
    float* __restrict__ out, float* __restrict__ out_states,
    int* __restrict__ ticket, int* __restrict__ flags,
    float* __restrict__ agg) {
  __shared__ float smaps[F][MROW];
  __shared__ float red[F][RROW];
  __shared__ float2 sgb[F];
  __shared__ int vbid_sh;

  int tid = threadIdx.x;
  if (tid == 0) {
    vbid_sh = __hip_atomic_fetch_add(ticket, 1, __ATOMIC_RELAXED,
                                     __HIP_MEMORY_SCOPE_AGENT);
  }
  __syncthreads();
  int bg = vbid_sh;
  int b = bg / NG, g = bg % NG;
  int c0 = g * GS;
  int nc = (C - c0 < GS) ? (C - c0) : GS;
  int c_local = tid / F, f = tid % F;
  int w = tid >> 6, lane = tid & 63;

  // ---- build chunk map (pipelined loads, R9 pattern) ----
  {
    float u1 = 1.f, u2 = 0.f, v1 = 0.f, v2 = 1.f, w1 = 0.f, w2 = 0.f;
    if (c_local < nc) {
      int c = c0 + c_local;
      const float* cfp = cf + ((size_t)b * T + c * L) * F + f;
      const float* bwp = bw + ((size_t)b * T + c * L) * F + f;
      const float4* ep4 = (const float4*)(exc + (size_t)b * T + c * L);

      float4 e = ep4[0];
      float cfa[4], bwa[4];
      #pragma unroll
      for (int j = 0; j < 4; ++j) { cfa[j] = cfp[j * F]; bwa[j] = bwp[j * F]; }

      #pragma unroll
      for (int tile = 0; tile < 4; ++tile) {
        float4 en;
        float cfn[4], bwn[4];
        if (tile < 3) {
          en = ep4[tile + 1];
          #pragma unroll
          for (int j = 0; j < 4; ++j) {
            cfn[j] = cfp[(tile * 4 + 4 + j) * F];
            bwn[j] = bwp[(tile * 4 + 4 + j) * F];
          }
        }
        #pragma unroll
        for (int j = 0; j < 4; ++j) {
          float p, q, x;
          coef(cfa[j], bwa[j], (&e.x)[j], p, q, x);
          float nu = fmaf(p, u1, q * u2);
          float nv = fmaf(p, v1, q * v2);
          float nw = fmaf(p, w1, fmaf(q, w2, x));
          u2 = u1; u1 = nu;
          v2 = v1; v1 = nv;
          w2 = w1; w1 = nw;
        }
        if (tile < 3) {
          e = en;
          #pragma unroll
          for (int j = 0; j < 4; ++j) { cfa[j] = cfn[j]; bwa[j] = bwn[j]; }
        }
      }
    }
    float* m = &smaps[f][c_local * MSTRIDE];
    m[0] = u1; m[1] = u2; m[2] = v1; m[3] = v2; m[4] = w1; m[5] = w2;
  }
  __syncthreads();

  // ---- in-LDS wave-per-formant inclusive scan; publish aggregate ----
  int chain = b * F + w;
  {
    float* s = &smaps[w][lane * MSTRIDE];
    float a1 = s[0], a2 = s[1], a3 = s[2], a4 = s[3], a5 = s[4], a6 = s[5];
    wave_scan_maps(lane, a1, a2, a3, a4, a5, a6);
    // write back scanned maps (each lane owns its slot; wave-synchronous)
    s[0] = a1; s[1] = a2; s[2] = a3; s[3] = a4; s[4] = a5; s[5] = a6;

    if (lane == 63) {   // group aggregate (identity pads keep it exact)
      float* a = agg + (size_t)(chain * NG + g) * 8;
      __hip_atomic_store(&a[0], a1, __ATOMIC_RELAXED, __HIP_MEMORY_SCOPE_AGENT);
      __hip_atomic_store(&a[1], a2, __ATOMIC_RELAXED, __HIP_MEMORY_SCOPE_AGENT);
      __hip_atomic_store(&a[2], a3, __ATOMIC_RELAXED, __HIP_MEMORY_SCOPE_AGENT);
      __hip_atomic_store(&a[3], a4, __ATOMIC_RELAXED, __HIP_MEMORY_SCOPE_AGENT);
      __hip_atomic_store(&a[4], a5, __ATOMIC_RELAXED, __HIP_MEMORY_SCOPE_AGENT);
      __hip_atomic_store(&a[5], a6, __ATOMIC_RELAXED, __HIP_MEMORY_SCOPE_AGENT);
      __hip_atomic_store(&flags[chain * NG + g], 1, __ATOMIC_RELEASE,
                         __HIP_MEMORY_SCOPE_AGENT);
    }
  }

  // ---- look-back: compose predecessor aggregates (lane i = group i) ----
  {
    float s01 = states0[chain * 2 + 0];
    float s02 = states0[chain * 2 + 1];
    float sy1 = s01, sy2 = s02;
    if (g > 0) {
      bool mine = lane < g;
      if (mine) {
        const int* fl = &flags[chain * NG + lane];
        while (__hip_atomic_load(fl, __ATOMIC_ACQUIRE,
                                 __HIP_MEMORY_SCOPE_AGENT) == 0) {
          __builtin_amdgcn_s_sleep(2);
        }
      }
      float u1 = 1.f, u2 = 0.f, v1 = 0.f, v2 = 1.f, w1 = 0.f, w2 = 0.f;
      if (mine) {
        const float* a = agg + (size_t)(chain * NG + lane) * 8;
        u1 = __hip_atomic_load(&a[0], __ATOMIC_RELAXED, __HIP_MEMORY_SCOPE_AGENT);
        u2 = __hip_atomic_load(&a[1], __ATOMIC_RELAXED, __HIP_MEMORY_SCOPE_AGENT);
        v1 = __hip_atomic_load(&a[2], __ATOMIC_RELAXED, __HIP_MEMORY_SCOPE_AGENT);
        v2 = __hip_atomic_load(&a[3], __ATOMIC_RELAXED, __HIP_MEMORY_SCOPE_AGENT);
        w1 = __hip_atomic_load(&a[4], __ATOMIC_RELAXED, __HIP_MEMORY_SCOPE_AGENT);
        w2 = __hip_atomic_load(&a[5], __ATOMIC_RELAXED, __HIP_MEMORY_SCOPE_AGENT);
      }
      wave_scan_maps(lane, u1, u2, v1, v2, w1, w2);
      // product of groups 0..g-1 sits at lane 63 (identity pads above g-1)
      u1 = __shfl(u1, 63); u2 = __shfl(u2, 63);
      v1 = __shfl(v1, 63); v2 = __shfl(v2, 63);
      w1 = __shfl(w1, 63); w2 = __shfl(w2, 63);
      sy1 = fmaf(u1, s01, fmaf(v1, s02, w1));
      sy2 = fmaf(u2, s01, fmaf(v2, s02, w2));
    }
    if (lane == 0) sgb[w] = make_float2(sy1, sy2);

    // new_states: last group's block composes its own aggregate on top
    if (g == NG - 1 && lane == 63) {
      const float* s = &smaps[w][63 * MSTRIDE];
      out_states[chain * 2 + 0] = fmaf(s[0], sy1, fmaf(s[2], sy2, s[4]));
      out_states[chain * 2 + 1] = fmaf(s[1], sy1, fmaf(s[3], sy2, s[5]));
    }
  }
  __syncthreads();

  // ---- replay (inputs L1/L2-hot from build) ----
  if (c_local < nc) {
    int c = c0 + c_local;
    float2 sg = sgb[f];
    float y1, y2;
    if (c_local == 0) {
      y1 = sg.x; y2 = sg.y;
    } else {
      const float* m = &smaps[f][(c_local - 1) * MSTRIDE];
      y1 = fmaf(m[0], sg.x, fmaf(m[2], sg.y, m[4]));
      y2 = fmaf(m[1], sg.x, fmaf(m[3], sg.y, m[5]));
    }

    const float* cfp = cf + ((size_t)b * T + c * L) * F + f;
    const float* bwp = bw + ((size_t)b * T + c * L) * F + f;
    const float4* ep4 = (const float4*)(exc + (size_t)b * T + c * L);

    float4 e = ep4[0];
    float cfa[4], bwa[4];
    #pragma unroll
    for (int j = 0; j < 4; ++j) { cfa[j] = cfp[j * F]; bwa[j] = bwp[j * F]; }

    float* rrow = &red[f][c_local * (L + 1)];
    #pragma unroll
    for (int tile = 0; tile < 4; ++tile) {
      float4 en;
      float cfn[4], bwn[4];
      if (tile < 3) {
        en = ep4[tile + 1];
        #pragma unroll
        for (int j = 0; j < 4; ++j) {
          cfn[j] = cfp[(tile * 4 + 4 + j) * F];
          bwn[j] = bwp[(tile * 4 + 4 + j) * F];
        }
      }
      #pragma unroll
      for (int j = 0; j < 4; ++j) {
        float p, q, x;
        coef(cfa[j], bwa[j], (&e.x)[j], p, q, x);
        float y = fmaf(p, y1, fmaf(q, y2, x));
        rrow[tile * 4 + j] = y;
        y2 = y1;
        y1 = y;
      }
      if (tile < 3) {
        e = en;
        #pragma unroll
        for (int j = 0; j < 4; ++j) { cfa[j] = cfn[j]; bwa[j] = bwn[j]; }
      }
    }
  }
  __syncthreads();

  // ---- f-sum + coalesced store ----
  int nt = nc * L;
  size_t tbase = (size_t)b * T + (size_t)c0 * L;
  for (int t = tid; t < nt; t += THREADS) {
    int a = (t >> 4) * (L + 1) + (t & (L - 1));
    float s = red[0][a] + red[1][a] + red[2][a] + red[3][a] + red[4][a];
    out[tbase + t] = s;
  }
}

extern "C" void kernel_launch(void* const* d_in, const int* in_sizes, int n_in,
                              void* d_out, int out_size, void* d_ws, size_t ws_size,
                              hipStream_t stream) {
  const float* exc = (const float*)d_in[0];   // (B,T,1)
  const float* cf  = (const float*)d_in[1];   // (B,T,F)
  const float* bw  = (const float*)d_in[2];   // (B,T,F)
  const float* st  = (const float*)d_in[3];   // (B,F,2)
  float* out        = (float*)d_out;          // (B,T,1) then (B,F,2)
  float* out_states = out + (size_t)B * T;

  // ws layout: [ticket int][pad to 256B][flags NCHAIN*NG ints][agg @32KB]
  int* ticket  = (int*)d_ws;
  int* flags   = (int*)((char*)d_ws + 256);
  float* agg   = (float*)((char*)d_ws + (1 << 15));  // 32KB offset

  // zero ticket + flags each call (captured in graph -> re-runs every replay)
  hipMemsetAsync(d_ws, 0, 1 << 15, stream);

  fused_kernel<<<NBG, THREADS, 0, stream>>>(exc, cf, bw, st, out, out_states,
                                            ticket, flags, agg);
}

// Round 11
// 231.433 us; speedup vs baseline: 2.4877x; 2.4877x over previous
//
#include <hip/hip_runtime.h>

// StatefulFormantFilter: B=32, T=48000, F=5
// y[t] = x[t] + 2 r cos(th) y[t-1] - r^2 y[t-2],  r=exp(-pi bw/SR), th=2 pi cf/SR
// x = excitation * (1-r^2) sin(th);  out = sum_f y;  new_states = (y[T-1], y[T-2])
//
// R11 = R10 single-pass decoupled-lookback, with the poll path rebuilt:
//  - R10 failure mode: ACQUIRE poll loop = vL1 invalidate per iteration ->
//    chip-wide cache-invalidate storm (575us, VALUBusy 1.5%).
//  - Fix: poll + aggregate reads are relaxed atomic RMWs (fetch_add 0) --
//    served at the coherence point, NO cache invalidation; s_sleep backoff.
//  - Publishes depend only on local build (never wait) -> no serial cascade;
//    ticket order makes lookback deadlock-free.

constexpr int B = 32;
constexpr int T = 48000;
constexpr int F = 5;
constexpr int L = 16;          // chunk length
constexpr int C = T / L;       // 3000 chunks per chain
constexpr int GS = 64;         // chunks per group (one wave per formant)
constexpr int NG = (C + GS - 1) / GS;  // 47 groups per chain (<= 64)
constexpr int NCHAIN = B * F;  // 160
constexpr int THREADS = GS * F;        // 320 = 5 waves
constexpr int NBG = B * NG;            // 1504 blocks
constexpr int MSTRIDE = 7;             // map stride in floats
constexpr int MROW = GS * MSTRIDE + 1; // 449: row ≡ 1 mod 32 -> bank spread
constexpr int RROW = GS * (L + 1) + 1; // 1089

#define CBW2 (-9.4416635e-05f)   // -pi/(48000*ln2)
#define CCF  (1.3089969e-04f)    // 2*pi/48000

__device__ __forceinline__ float fast_exp2(float x) {
#if __has_builtin(__builtin_amdgcn_exp2f)
  return __builtin_amdgcn_exp2f(x);
#else
  return exp2f(x);
#endif
}

__device__ __forceinline__ void coef(float cff, float bwf, float e,
                                     float& p, float& q, float& x) {
  float r  = fast_exp2(CBW2 * bwf);
  float th = CCF * cff;
  float sn = __sinf(th);
  float cs = __cosf(th);
  p = 2.f * r * cs;            // -a1
  q = -r * r;                  // -a2
  x = e * fmaf(q, sn, sn);     // e * (1-r^2) sin(th)
}

// Inclusive Hillis-Steele scan of affine maps across a wave.
__device__ __forceinline__ void wave_scan_maps(int lane, float& u1, float& u2,
                                               float& v1, float& v2,
                                               float& w1, float& w2) {
  #pragma unroll
  for (int d = 1; d < 64; d <<= 1) {
    float pu1 = __shfl_up(u1, d);
    float pv1 = __shfl_up(v1, d);
    float pu2 = __shfl_up(u2, d);
    float pv2 = __shfl_up(v2, d);
    float pw1 = __shfl_up(w1, d);
    float pw2 = __shfl_up(w2, d);
    bool has = (lane >= d);
    pu1 = has ? pu1 : 1.f;  pv1 = has ? pv1 : 0.f;
    pu2 = has ? pu2 : 0.f;  pv2 = has ? pv2 : 1.f;
    pw1 = has ? pw1 : 0.f;  pw2 = has ? pw2 : 0.f;
    float nu1 = fmaf(u1, pu1, v1 * pu2);
    float nv1 = fmaf(u1, pv1, v1 * pv2);
    float nu2 = fmaf(u2, pu1, v2 * pu2);
    float nv2 = fmaf(u2, pv1, v2 * pv2);
    float nw1 = fmaf(u1, pw1, fmaf(v1, pw2, w1));
    float nw2 = fmaf(u2, pw1, fmaf(v2, pw2, w2));
    u1 = nu1; v1 = nv1; u2 = nu2; v2 = nv2; w1 = nw1; w2 = nw2;
  }
}

__global__ __launch_bounds__(THREADS) void fused_kernel(
    const float* __restrict__ exc, const float* __restrict__ cf,
    const float* __restrict__ bw, const float* __restrict__ states0,
    float* __restrict__ out, float* __restrict__ out_states,
    int* __restrict__ ticket, int* __restrict__ flags,
    float* __restrict__ agg) {
  __shared__ float smaps[F][MROW];
  __shared__ float red[F][RROW];
  __shared__ float2 sgb[F];
  __shared__ int vbid_sh;

  int tid = threadIdx.x;
  if (tid == 0) {
    vbid_sh = __hip_atomic_fetch_add(ticket, 1, __ATOMIC_RELAXED,
                                     __HIP_MEMORY_SCOPE_AGENT);
  }
  __syncthreads();
  int bg = vbid_sh;
  int b = bg / NG, g = bg % NG;
  int c0 = g * GS;
  int nc = (C - c0 < GS) ? (C - c0) : GS;
  int c_local = tid / F, f = tid % F;
  int w = tid >> 6, lane = tid & 63;

  // ---- build chunk map (pipelined loads) ----
  {
    float u1 = 1.f, u2 = 0.f, v1 = 0.f, v2 = 1.f, w1 = 0.f, w2 = 0.f;
    if (c_local < nc) {
      int c = c0 + c_local;
      const float* cfp = cf + ((size_t)b * T + c * L) * F + f;
      const float* bwp = bw + ((size_t)b * T + c * L) * F + f;
      const float4* ep4 = (const float4*)(exc + (size_t)b * T + c * L);

      float4 e = ep4[0];
      float cfa[4], bwa[4];
      #pragma unroll
      for (int j = 0; j < 4; ++j) { cfa[j] = cfp[j * F]; bwa[j] = bwp[j * F]; }

      #pragma unroll
      for (int tile = 0; tile < 4; ++tile) {
        float4 en;
        float cfn[4], bwn[4];
        if (tile < 3) {
          en = ep4[tile + 1];
          #pragma unroll
          for (int j = 0; j < 4; ++j) {
            cfn[j] = cfp[(tile * 4 + 4 + j) * F];
            bwn[j] = bwp[(tile * 4 + 4 + j) * F];
          }
        }
        #pragma unroll
        for (int j = 0; j < 4; ++j) {
          float p, q, x;
          coef(cfa[j], bwa[j], (&e.x)[j], p, q, x);
          float nu = fmaf(p, u1, q * u2);
          float nv = fmaf(p, v1, q * v2);
          float nw = fmaf(p, w1, fmaf(q, w2, x));
          u2 = u1; u1 = nu;
          v2 = v1; v1 = nv;
          w2 = w1; w1 = nw;
        }
        if (tile < 3) {
          e = en;
          #pragma unroll
          for (int j = 0; j < 4; ++j) { cfa[j] = cfn[j]; bwa[j] = bwn[j]; }
        }
      }
    }
    float* m = &smaps[f][c_local * MSTRIDE];
    m[0] = u1; m[1] = u2; m[2] = v1; m[3] = v2; m[4] = w1; m[5] = w2;
  }
  __syncthreads();

  // ---- in-LDS wave-per-formant inclusive scan; publish aggregate ----
  int chain = b * F + w;
  {
    float* s = &smaps[w][lane * MSTRIDE];
    float a1 = s[0], a2 = s[1], a3 = s[2], a4 = s[3], a5 = s[4], a6 = s[5];
    wave_scan_maps(lane, a1, a2, a3, a4, a5, a6);
    s[0] = a1; s[1] = a2; s[2] = a3; s[3] = a4; s[4] = a5; s[5] = a6;

    if (lane == 63) {   // group aggregate (identity pads keep it exact)
      float* a = agg + (size_t)(chain * NG + g) * 8;
      __hip_atomic_store(&a[0], a1, __ATOMIC_RELAXED, __HIP_MEMORY_SCOPE_AGENT);
      __hip_atomic_store(&a[1], a2, __ATOMIC_RELAXED, __HIP_MEMORY_SCOPE_AGENT);
      __hip_atomic_store(&a[2], a3, __ATOMIC_RELAXED, __HIP_MEMORY_SCOPE_AGENT);
      __hip_atomic_store(&a[3], a4, __ATOMIC_RELAXED, __HIP_MEMORY_SCOPE_AGENT);
      __hip_atomic_store(&a[4], a5, __ATOMIC_RELAXED, __HIP_MEMORY_SCOPE_AGENT);
      __hip_atomic_store(&a[5], a6, __ATOMIC_RELAXED, __HIP_MEMORY_SCOPE_AGENT);
      __hip_atomic_store(&flags[chain * NG + g], 1, __ATOMIC_RELEASE,
                         __HIP_MEMORY_SCOPE_AGENT);
    }
  }

  // ---- look-back: RMW-based (coherence-point reads, NO cache invalidates) ----
  {
    float s01 = states0[chain * 2 + 0];
    float s02 = states0[chain * 2 + 1];
    float sy1 = s01, sy2 = s02;
    if (g > 0) {
      bool mine = lane < g;
      if (mine) {
        int* fl = &flags[chain * NG + lane];
        // relaxed RMW poll: served at coherence point, no vL1 invalidation
        while (__hip_atomic_fetch_add(fl, 0, __ATOMIC_RELAXED,
                                      __HIP_MEMORY_SCOPE_AGENT) == 0) {
          __builtin_amdgcn_s_sleep(16);
        }
      }
      float u1 = 1.f, u2 = 0.f, v1 = 0.f, v2 = 1.f, w1 = 0.f, w2 = 0.f;
      if (mine) {
        // flag-gated: writer's stores complete before flag; RMW reads are
        // tear-free 8B and bypass stale caches.
        unsigned long long* a8 =
            (unsigned long long*)(agg + (size_t)(chain * NG + lane) * 8);
        unsigned long long p01 = __hip_atomic_fetch_add(
            &a8[0], 0ull, __ATOMIC_RELAXED, __HIP_MEMORY_SCOPE_AGENT);
        unsigned long long p23 = __hip_atomic_fetch_add(
            &a8[1], 0ull, __ATOMIC_RELAXED, __HIP_MEMORY_SCOPE_AGENT);
        unsigned long long p45 = __hip_atomic_fetch_add(
            &a8[2], 0ull, __ATOMIC_RELAXED, __HIP_MEMORY_SCOPE_AGENT);
        u1 = __uint_as_float((unsigned)p01);
        u2 = __uint_as_float((unsigned)(p01 >> 32));
        v1 = __uint_as_float((unsigned)p23);
        v2 = __uint_as_float((unsigned)(p23 >> 32));
        w1 = __uint_as_float((unsigned)p45);
        w2 = __uint_as_float((unsigned)(p45 >> 32));
      }
      wave_scan_maps(lane, u1, u2, v1, v2, w1, w2);
      // product of groups 0..g-1 sits at lane 63 (identity pads above g-1)
      u1 = __shfl(u1, 63); u2 = __shfl(u2, 63);
      v1 = __shfl(v1, 63); v2 = __shfl(v2, 63);
      w1 = __shfl(w1, 63); w2 = __shfl(w2, 63);
      sy1 = fmaf(u1, s01, fmaf(v1, s02, w1));
      sy2 = fmaf(u2, s01, fmaf(v2, s02, w2));
    }
    if (lane == 0) sgb[w] = make_float2(sy1, sy2);

    // new_states: last group's block composes its own aggregate on top
    if (g == NG - 1 && lane == 63) {
      const float* s = &smaps[w][63 * MSTRIDE];
      out_states[chain * 2 + 0] = fmaf(s[0], sy1, fmaf(s[2], sy2, s[4]));
      out_states[chain * 2 + 1] = fmaf(s[1], sy1, fmaf(s[3], sy2, s[5]));
    }
  }
  __syncthreads();

  // ---- replay (inputs L1/L2-hot from build) ----
  if (c_local < nc) {
    int c = c0 + c_local;
    float2 sg = sgb[f];
    float y1, y2;
    if (c_local == 0) {
      y1 = sg.x; y2 = sg.y;
    } else {
      const float* m = &smaps[f][(c_local - 1) * MSTRIDE];
      y1 = fmaf(m[0], sg.x, fmaf(m[2], sg.y, m[4]));
      y2 = fmaf(m[1], sg.x, fmaf(m[3], sg.y, m[5]));
    }

    const float* cfp = cf + ((size_t)b * T + c * L) * F + f;
    const float* bwp = bw + ((size_t)b * T + c * L) * F + f;
    const float4* ep4 = (const float4*)(exc + (size_t)b * T + c * L);

    float4 e = ep4[0];
    float cfa[4], bwa[4];
    #pragma unroll
    for (int j = 0; j < 4; ++j) { cfa[j] = cfp[j * F]; bwa[j] = bwp[j * F]; }

    float* rrow = &red[f][c_local * (L + 1)];
    #pragma unroll
    for (int tile = 0; tile < 4; ++tile) {
      float4 en;
      float cfn[4], bwn[4];
      if (tile < 3) {
        en = ep4[tile + 1];
        #pragma unroll
        for (int j = 0; j < 4; ++j) {
          cfn[j] = cfp[(tile * 4 + 4 + j) * F];
          bwn[j] = bwp[(tile * 4 + 4 + j) * F];
        }
      }
      #pragma unroll
      for (int j = 0; j < 4; ++j) {
        float p, q, x;
        coef(cfa[j], bwa[j], (&e.x)[j], p, q, x);
        float y = fmaf(p, y1, fmaf(q, y2, x));
        rrow[tile * 4 + j] = y;
        y2 = y1;
        y1 = y;
      }
      if (tile < 3) {
        e = en;
        #pragma unroll
        for (int j = 0; j < 4; ++j) { cfa[j] = cfn[j]; bwa[j] = bwn[j]; }
      }
    }
  }
  __syncthreads();

  // ---- f-sum + coalesced store ----
  int nt = nc * L;
  size_t tbase = (size_t)b * T + (size_t)c0 * L;
  for (int t = tid; t < nt; t += THREADS) {
    int a = (t >> 4) * (L + 1) + (t & (L - 1));
    float s = red[0][a] + red[1][a] + red[2][a] + red[3][a] + red[4][a];
    out[tbase + t] = s;
  }
}

extern "C" void kernel_launch(void* const* d_in, const int* in_sizes, int n_in,
                              void* d_out, int out_size, void* d_ws, size_t ws_size,
                              hipStream_t stream) {
  const float* exc = (const float*)d_in[0];   // (B,T,1)
  const float* cf  = (const float*)d_in[1];   // (B,T,F)
  const float* bw  = (const float*)d_in[2];   // (B,T,F)
  const float* st  = (const float*)d_in[3];   // (B,F,2)
  float* out        = (float*)d_out;          // (B,T,1) then (B,F,2)
  float* out_states = out + (size_t)B * T;

  // ws layout: [ticket int][pad to 256B][flags NCHAIN*NG ints][agg @32KB]
  int* ticket  = (int*)d_ws;
  int* flags   = (int*)((char*)d_ws + 256);
  float* agg   = (float*)((char*)d_ws + (1 << 15));  // 32KB offset

  // zero ticket + flags each call (inside graph -> re-runs every replay)
  hipMemsetAsync(d_ws, 0, 1 << 15, stream);

  fused_kernel<<<NBG, THREADS, 0, stream>>>(exc, cf, bw, st, out, out_states,
                                            ticket, flags, agg);
}

// Round 12
// 42.542 us; speedup vs baseline: 13.5337x; 5.4402x over previous
//
#include <hip/hip_runtime.h>

// StatefulFormantFilter: B=32, T=48000, F=5
// y[t] = x[t] + 2 r cos(th) y[t-1] - r^2 y[t-2],  r=exp(-pi bw/SR), th=2 pi cf/SR
// x = excitation * (1-r^2) sin(th);  out = sum_f y;  new_states = (y[T-1], y[T-2])
//
// R12 = R9 (best, 43.0us) + micro-cuts:
//  - Aws maps stored as 6 floats (3x float2), was 8 (2x float4): -25% map traffic.
//  - sin/cos via raw v_sin/v_cos with REVOLUTION input (cf/48000, no fract
//    needed: rev < 0.084) — drops radians->rev mul + fract per trans op.
// Ledger of closed paths: LDS-staged inputs (R7, -10us: occupancy), coop
// grid.sync (R8: ~75us/sync), lookback acquire-poll (R10: invalidate storm),
// lookback RMW-poll (R11: coherence-point serialization).

constexpr int B = 32;
constexpr int T = 48000;
constexpr int F = 5;
constexpr int L = 16;          // chunk length
constexpr int C = T / L;       // 3000 chunks per chain
constexpr int GS = 64;         // chunks per group (one wave per formant)
constexpr int NG = (C + GS - 1) / GS;  // 47 groups
constexpr int NCHAIN = B * F;  // 160
constexpr int THREADS = GS * F;        // 320 = 5 waves
constexpr int NBG = B * NG;            // 1504 (b,group) tiles
constexpr int MSTRIDE = 7;             // LDS map stride in floats
constexpr int MROW = GS * MSTRIDE + 1; // 449: row ≡ 1 mod 32 -> bank spread
constexpr int RROW = GS * (L + 1) + 1; // 1089

#define CBW2 (-9.4416635e-05f)   // -pi/(48000*ln2)   (exp2 scale)
#define CREV (2.0833333e-05f)    // 1/48000           (revolutions scale)

__device__ __forceinline__ float fast_exp2(float x) {
#if __has_builtin(__builtin_amdgcn_exp2f)
  return __builtin_amdgcn_exp2f(x);
#else
  return exp2f(x);
#endif
}

__device__ __forceinline__ void coef(float cff, float bwf, float e,
                                     float& p, float& q, float& x) {
  float r = fast_exp2(CBW2 * bwf);
#if __has_builtin(__builtin_amdgcn_sinf) && __has_builtin(__builtin_amdgcn_cosf)
  // v_sin/v_cos take revolutions: sin(2*pi*rev). rev in [0.004,0.084] -> no fract.
  float rev = CREV * cff;
  float sn = __builtin_amdgcn_sinf(rev);
  float cs = __builtin_amdgcn_cosf(rev);
#else
  float th = 6.2831853e+00f * CREV * cff;
  float sn = __sinf(th);
  float cs = __cosf(th);
#endif
  p = 2.f * r * cs;            // -a1
  q = -r * r;                  // -a2
  x = e * fmaf(q, sn, sn);     // e * (1-r^2) sin(th)
}

// Inclusive Hillis-Steele scan of affine maps across a wave (newest-on-left).
__device__ __forceinline__ void wave_scan_maps(int lane, float& u1, float& u2,
                                               float& v1, float& v2,
                                               float& w1, float& w2) {
  #pragma unroll
  for (int d = 1; d < 64; d <<= 1) {
    float pu1 = __shfl_up(u1, d);
    float pv1 = __shfl_up(v1, d);
    float pu2 = __shfl_up(u2, d);
    float pv2 = __shfl_up(v2, d);
    float pw1 = __shfl_up(w1, d);
    float pw2 = __shfl_up(w2, d);
    bool has = (lane >= d);
    pu1 = has ? pu1 : 1.f;  pv1 = has ? pv1 : 0.f;
    pu2 = has ? pu2 : 0.f;  pv2 = has ? pv2 : 1.f;
    pw1 = has ? pw1 : 0.f;  pw2 = has ? pw2 : 0.f;
    float nu1 = fmaf(u1, pu1, v1 * pu2);
    float nv1 = fmaf(u1, pv1, v1 * pv2);
    float nu2 = fmaf(u2, pu1, v2 * pu2);
    float nv2 = fmaf(u2, pv1, v2 * pv2);
    float nw1 = fmaf(u1, pw1, fmaf(v1, pw2, w1));
    float nw2 = fmaf(u2, pw1, fmaf(v2, pw2, w2));
    u1 = nu1; v1 = nv1; u2 = nu2; v2 = nv2; w1 = nw1; w2 = nw2;
  }
}

__global__ __launch_bounds__(THREADS) void k1_kernel(
    const float* __restrict__ exc, const float* __restrict__ cf,
    const float* __restrict__ bw, float* __restrict__ Aws,
    float* __restrict__ Gprod) {
  __shared__ float smaps[F][MROW];

  int bg = blockIdx.x;
  int b = bg / NG, g = bg % NG;
  int tid = threadIdx.x;
  int c_local = tid / F, f = tid % F;
  int c = g * GS + c_local;

  float u1 = 1.f, u2 = 0.f, v1 = 0.f, v2 = 1.f, w1 = 0.f, w2 = 0.f;
  if (c < C) {
    const float* cfp = cf + ((size_t)b * T + c * L) * F + f;
    const float* bwp = bw + ((size_t)b * T + c * L) * F + f;
    const float4* ep4 = (const float4*)(exc + (size_t)b * T + c * L);

    float4 e = ep4[0];
    float cfa[4], bwa[4];
    #pragma unroll
    for (int j = 0; j < 4; ++j) { cfa[j] = cfp[j * F]; bwa[j] = bwp[j * F]; }

    #pragma unroll
    for (int tile = 0; tile < 4; ++tile) {
      float4 en;
      float cfn[4], bwn[4];
      if (tile < 3) {   // issue next tile's loads before computing this one
        en = ep4[tile + 1];
        #pragma unroll
        for (int j = 0; j < 4; ++j) {
          cfn[j] = cfp[(tile * 4 + 4 + j) * F];
          bwn[j] = bwp[(tile * 4 + 4 + j) * F];
        }
      }
      #pragma unroll
      for (int j = 0; j < 4; ++j) {
        float p, q, x;
        coef(cfa[j], bwa[j], (&e.x)[j], p, q, x);
        float nu = fmaf(p, u1, q * u2);
        float nv = fmaf(p, v1, q * v2);
        float nw = fmaf(p, w1, fmaf(q, w2, x));
        u2 = u1; u1 = nu;
        v2 = v1; v1 = nv;
        w2 = w1; w1 = nw;
      }
      if (tile < 3) {
        e = en;
        #pragma unroll
        for (int j = 0; j < 4; ++j) { cfa[j] = cfn[j]; bwa[j] = bwn[j]; }
      }
    }
  }

  {
    float* m = &smaps[f][c_local * MSTRIDE];
    m[0] = u1; m[1] = u2; m[2] = v1; m[3] = v2; m[4] = w1; m[5] = w2;
  }
  __syncthreads();

  int w = tid >> 6, lane = tid & 63;
  const float* s = &smaps[w][lane * MSTRIDE];
  float a1 = s[0], a2 = s[1], a3 = s[2], a4 = s[3], a5 = s[4], a6 = s[5];
  wave_scan_maps(lane, a1, a2, a3, a4, a5, a6);

  int c2 = g * GS + lane;
  int chain = b * F + w;
  if (c2 < C) {
    float2* o = (float2*)(Aws + ((size_t)chain * C + c2) * 6);
    o[0] = make_float2(a1, a2);
    o[1] = make_float2(a3, a4);
    o[2] = make_float2(a5, a6);
  }
  if (lane == 63) {
    float4* gp = (float4*)(Gprod + (size_t)(chain * NG + g) * 8);
    gp[0] = make_float4(a1, a2, a3, a4);
    gp[1] = make_float4(a5, a6, 0.f, 0.f);
  }
}

__global__ __launch_bounds__(THREADS) void k3_kernel(
    const float* __restrict__ exc, const float* __restrict__ cf,
    const float* __restrict__ bw, const float* __restrict__ Aws,
    const float* __restrict__ Gprod, const float* __restrict__ states0,
    float* __restrict__ out, float* __restrict__ out_states) {
  __shared__ float red[F][RROW];
  __shared__ float2 sgb[F];

  int bg = blockIdx.x;
  int b = bg / NG, g = bg % NG;
  int c0 = g * GS;
  int nc = (C - c0 < GS) ? (C - c0) : GS;
  int tid = threadIdx.x;
  int c_local = tid / F, f = tid % F;
  int w = tid >> 6, lane = tid & 63;

  // --- per-block chain prefix: wave w scans formant w's 47 group products ---
  {
    int chain = b * F + w;
    float u1 = 1.f, u2 = 0.f, v1 = 0.f, v2 = 1.f, w1 = 0.f, w2 = 0.f;
    if (lane < NG) {
      const float4* gp = (const float4*)(Gprod + (size_t)(chain * NG + lane) * 8);
      float4 A0 = gp[0];
      float4 A1 = gp[1];
      u1 = A0.x; u2 = A0.y; v1 = A0.z; v2 = A0.w; w1 = A1.x; w2 = A1.y;
    }
    wave_scan_maps(lane, u1, u2, v1, v2, w1, w2);

    float s01 = states0[chain * 2 + 0];
    float s02 = states0[chain * 2 + 1];
    if (g == 0) {
      if (lane == 0) sgb[w] = make_float2(s01, s02);
      if (lane == NG - 1) {   // full-chain product -> new_states (once per chain)
        out_states[chain * 2 + 0] = fmaf(u1, s01, fmaf(v1, s02, w1));
        out_states[chain * 2 + 1] = fmaf(u2, s01, fmaf(v2, s02, w2));
      }
    } else if (lane == g - 1) {  // exclusive prefix before group g
      float sy1 = fmaf(u1, s01, fmaf(v1, s02, w1));
      float sy2 = fmaf(u2, s01, fmaf(v2, s02, w2));
      sgb[w] = make_float2(sy1, sy2);
    }
  }
  __syncthreads();

  // --- replay ---
  if (c_local < nc) {
    int c = c0 + c_local;
    int chain = b * F + f;

    float2 sg = sgb[f];
    float y1, y2;
    if (c_local == 0) {
      y1 = sg.x; y2 = sg.y;
    } else {
      const float2* m = (const float2*)(Aws + ((size_t)chain * C + (c - 1)) * 6);
      float2 M0 = m[0];   // (u1,u2)
      float2 M1 = m[1];   // (v1,v2)
      float2 M2 = m[2];   // (w1,w2)
      y1 = fmaf(M0.x, sg.x, fmaf(M1.x, sg.y, M2.x));
      y2 = fmaf(M0.y, sg.x, fmaf(M1.y, sg.y, M2.y));
    }

    const float* cfp = cf + ((size_t)b * T + c * L) * F + f;
    const float* bwp = bw + ((size_t)b * T + c * L) * F + f;
    const float4* ep4 = (const float4*)(exc + (size_t)b * T + c * L);

    float4 e = ep4[0];
    float cfa[4], bwa[4];
    #pragma unroll
    for (int j = 0; j < 4; ++j) { cfa[j] = cfp[j * F]; bwa[j] = bwp[j * F]; }

    float* rrow = &red[f][c_local * (L + 1)];
    #pragma unroll
    for (int tile = 0; tile < 4; ++tile) {
      float4 en;
      float cfn[4], bwn[4];
      if (tile < 3) {
        en = ep4[tile + 1];
        #pragma unroll
        for (int j = 0; j < 4; ++j) {
          cfn[j] = cfp[(tile * 4 + 4 + j) * F];
          bwn[j] = bwp[(tile * 4 + 4 + j) * F];
        }
      }
      #pragma unroll
      for (int j = 0; j < 4; ++j) {
        float p, q, x;
        coef(cfa[j], bwa[j], (&e.x)[j], p, q, x);
        float y = fmaf(p, y1, fmaf(q, y2, x));
        rrow[tile * 4 + j] = y;
        y2 = y1;
        y1 = y;
      }
      if (tile < 3) {
        e = en;
        #pragma unroll
        for (int j = 0; j < 4; ++j) { cfa[j] = cfn[j]; bwa[j] = bwn[j]; }
      }
    }
  }
  __syncthreads();

  // --- f-sum + coalesced store ---
  int nt = nc * L;
  size_t tbase = (size_t)b * T + (size_t)c0 * L;
  for (int t = tid; t < nt; t += THREADS) {
    int a = (t >> 4) * (L + 1) + (t & (L - 1));
    float s = red[0][a] + red[1][a] + red[2][a] + red[3][a] + red[4][a];
    out[tbase + t] = s;
  }
}

extern "C" void kernel_launch(void* const* d_in, const int* in_sizes, int n_in,
                              void* d_out, int out_size, void* d_ws, size_t ws_size,
                              hipStream_t stream) {
  const float* exc = (const float*)d_in[0];   // (B,T,1)
  const float* cf  = (const float*)d_in[1];   // (B,T,F)
  const float* bw  = (const float*)d_in[2];   // (B,T,F)
  const float* st  = (const float*)d_in[3];   // (B,F,2)
  float* out        = (float*)d_out;          // (B,T,1) then (B,F,2)
  float* out_states = out + (size_t)B * T;

  float* Aws   = (float*)d_ws;                       // NCHAIN*C*6 floats = 11.52 MB
  float* Gprod = Aws + (size_t)NCHAIN * C * 6;       // NCHAIN*NG*8 floats = 240 KB

  k1_kernel<<<NBG, THREADS, 0, stream>>>(exc, cf, bw, Aws, Gprod);
  k3_kernel<<<NBG, THREADS, 0, stream>>>(exc, cf, bw, Aws, Gprod, st, out,
                                         out_states);
}